// Round 1
// baseline (70734.070 us; speedup 1.0000x reference)
//
#include <hip/hip_runtime.h>

#define IN_DIM   512
#define H_DIM    1024
#define OUT_DIM  256
#define B_DIM    64
#define S_DIM    256
#define UNFOLDS  6
#define EPS_F    1e-8f

#define GB       8    // batch groups (independent sync domains)
#define GH       32   // workgroups per group
#define BPG      8    // batches per group
#define JPW      32   // h-columns owned per WG
#define NTHREADS 512
#define NWG      (GB*GH)   // 256 = one per CU

#define LDS_FLOATS (JPW*H_DIM + BPG*H_DIM)   // 32768 + 8192 = 40960
#define LDS_BYTES  (LDS_FLOATS*4)            // 163840 B

#define OUT_Y_TOTAL ((size_t)B_DIM*S_DIM*OUT_DIM)

// ws layout (bytes): [0] h_buf0 (256KB) | [262144] h_buf1 (256KB)
//                    [524288] i_in (256KB) | [786432] counters (4KB)

__device__ __forceinline__ void group_barrier(unsigned int* ctr, unsigned int target) {
  __syncthreads();                       // all lanes' global h-writes drained (vmcnt)
  if (threadIdx.x == 0) {
    __threadfence();                     // agent release: flush to coherence point
    __hip_atomic_fetch_add(ctr, 1u, __ATOMIC_RELAXED, __HIP_MEMORY_SCOPE_AGENT);
    while (__hip_atomic_load(ctr, __ATOMIC_RELAXED, __HIP_MEMORY_SCOPE_AGENT) < target) {
      __builtin_amdgcn_s_sleep(2);
    }
    __threadfence();                     // agent acquire: invalidate stale L1/L2
  }
  __syncthreads();
}

__global__ void __launch_bounds__(NTHREADS)
ltc_kernel(const float* __restrict__ x, const float* __restrict__ h0,
           const float* __restrict__ tspan, const float* __restrict__ tau,
           const float* __restrict__ Wiw, const float* __restrict__ Wib,
           const float* __restrict__ Wrw, const float* __restrict__ wmask,
           const float* __restrict__ Wow, const float* __restrict__ Wob,
           const float* __restrict__ alpha_p, const float* __restrict__ beta_p,
           const float* __restrict__ mu_p, const float* __restrict__ sigma_p,
           float* __restrict__ out,
           float* __restrict__ hb0, float* __restrict__ hb1,
           float* __restrict__ iin_ws, unsigned int* __restrict__ counters)
{
  extern __shared__ float lds[];
  float* w_s = lds;                 // [JPW][H_DIM] masked w_rec slice
  float* h_s = lds + JPW*H_DIM;     // [BPG][H_DIM] staged h for this group

  const int tid = threadIdx.x;
  const int wg  = blockIdx.x;
  const int g   = wg & 7;           // group id: blockIdx%8 -> XCD co-location heuristic
  const int w   = wg >> 3;          // 0..31 within group
  const int b0g = g * BPG;
  const int jw0 = w * JPW;

  // ---- init: masked w_rec slice -> LDS
  for (int idx = tid; idx < JPW*H_DIM/4; idx += NTHREADS) {
    const int j  = idx >> 8;
    const int k4 = (idx & 255) << 2;
    const size_t go = (size_t)(jw0 + j)*H_DIM + k4;
    float4 wv = *(const float4*)(Wrw + go);
    float4 mv = *(const float4*)(wmask + go);
    wv.x *= mv.x; wv.y *= mv.y; wv.z *= mv.z; wv.w *= mv.w;
    *(float4*)&w_s[j*H_DIM + k4] = wv;
  }
  // ---- init h_buf0 from h0 (own slice)
  for (int idx = tid; idx < BPG*JPW; idx += NTHREADS) {
    const int b = idx >> 5;
    const int j = idx & 31;
    hb0[(size_t)(b0g + b)*H_DIM + jw0 + j] = h0[(size_t)(b0g + b)*H_DIM + jw0 + j];
  }
  // ---- W_in slice -> registers: thread (jj, kl) holds W_in[jw0+jj][kl*32 .. +32)
  const int jj = tid >> 4;          // 0..31
  const int kl = tid & 15;          // 0..15
  float win[32];
  {
    const float* src = Wiw + (size_t)(jw0 + jj)*IN_DIM + kl*32;
#pragma unroll
    for (int c = 0; c < 8; ++c) {
      float4 v = *(const float4*)(src + c*4);
      win[c*4+0] = v.x; win[c*4+1] = v.y; win[c*4+2] = v.z; win[c*4+3] = v.w;
    }
  }
  const float winb = Wib[jw0 + jj];

  unsigned int bar = 1;
  group_barrier(&counters[g], bar*GH); ++bar;   // h0 visible group-wide

  // stage h_buf0 -> h_s
  for (int idx = tid; idx < BPG*H_DIM/4; idx += NTHREADS) {
    const int b  = idx >> 8;
    const int k4 = (idx & 255) << 2;
    *(float4*)&h_s[b*H_DIM + k4] = *(const float4*)(hb0 + (size_t)(b0g + b)*H_DIM + k4);
  }
  __syncthreads();

  // i_rec mapping: ks = K-split lane (interleaved float4s -> conflict-free LDS),
  // each thread owns a 4b x 4j accumulator tile.
  const int ks  = tid & 31;
  const int ot  = tid >> 5;
  const int bb0 = (ot >> 3) << 2;   // 0 or 4
  const int jj0 = (ot & 7) << 2;    // 0,4,...,28

  for (int t = 0; t < S_DIM; ++t) {
    // ---- i_in for this step (x @ W_in.T + b), W_in in regs
#pragma unroll 1
    for (int b = 0; b < BPG; ++b) {
      const float* xr = x + ((size_t)(b0g + b)*S_DIM + t)*IN_DIM + kl*32;
      float s = 0.f;
#pragma unroll
      for (int c = 0; c < 8; ++c) {
        float4 v = *(const float4*)(xr + c*4);
        s += win[c*4+0]*v.x + win[c*4+1]*v.y + win[c*4+2]*v.z + win[c*4+3]*v.w;
      }
      s += __shfl_xor(s, 1, 64);
      s += __shfl_xor(s, 2, 64);
      s += __shfl_xor(s, 4, 64);
      s += __shfl_xor(s, 8, 64);
      if (kl == 0) iin_ws[((size_t)wg*BPG + b)*JPW + jj] = s + winb;
    }
    __syncthreads();   // iin_ws visible to whole WG (same-CU, after barrier+waitcnt)

#pragma unroll 1
    for (int u = 0; u < UNFOLDS; ++u) {
      float* hout = (u & 1) ? hb0 : hb1;   // ping-pong; step always ends in hb0

      float acc[16];
#pragma unroll
      for (int q = 0; q < 16; ++q) acc[q] = 0.f;
#pragma unroll
      for (int s8 = 0; s8 < 8; ++s8) {
        const int base = s8*128 + ks*4;    // lanes read consecutive float4s: no bank conflicts
        float4 hv[4], wv[4];
#pragma unroll
        for (int i = 0; i < 4; ++i) hv[i] = *(const float4*)&h_s[(bb0 + i)*H_DIM + base];
#pragma unroll
        for (int m = 0; m < 4; ++m) wv[m] = *(const float4*)&w_s[(jj0 + m)*H_DIM + base];
#pragma unroll
        for (int i = 0; i < 4; ++i)
#pragma unroll
          for (int m = 0; m < 4; ++m)
            acc[i*4+m] += hv[i].x*wv[m].x + hv[i].y*wv[m].y + hv[i].z*wv[m].z + hv[i].w*wv[m].w;
      }
#pragma unroll
      for (int d = 16; d >= 1; d >>= 1)
#pragma unroll
        for (int q = 0; q < 16; ++q)
          acc[q] += __shfl_xor(acc[q], d, 64);

      if (ks == 0) {
#pragma unroll
        for (int i = 0; i < 4; ++i) {
          const int b  = bb0 + i;
          const int gb = b0g + b;
          const float dsc = tspan[(size_t)gb*S_DIM + t] * (1.0f/UNFOLDS);
#pragma unroll
          for (int m = 0; m < 4; ++m) {
            const int j  = jj0 + m;
            const int gj = jw0 + j;
            const float irec = acc[i*4+m];
            const float hold = h_s[b*H_DIM + gj];
            const float z = (irec - mu_p[gj]) / (sigma_p[gj] + EPS_F);
            const float f = 1.0f / (1.0f + __expf(-z));
            const float iin = iin_ws[((size_t)wg*BPG + b)*JPW + j];
            const float dhdt = -alpha_p[gj]*hold + beta_p[gj]*f*(iin + irec);
            hout[(size_t)gb*H_DIM + gj] = hold + dsc*dhdt / tau[gj];
          }
        }
      }
      group_barrier(&counters[g], bar*GH); ++bar;
      // stage freshly-written h -> h_s (serves next unfold, y_t, next step)
      for (int idx = tid; idx < BPG*H_DIM/4; idx += NTHREADS) {
        const int b  = idx >> 8;
        const int k4 = (idx & 255) << 2;
        *(float4*)&h_s[b*H_DIM + k4] = *(const float4*)(hout + (size_t)(b0g + b)*H_DIM + k4);
      }
      __syncthreads();
    }

    // ---- y_t = h @ W_out.T + b (h_s holds end-of-step h)
    {
      const int o   = tid >> 3;     // 0..63
      const int ks8 = tid & 7;
      const int b   = o >> 3;
      const int oc  = w*8 + (o & 7);
      const float* worow = Wow + (size_t)oc*H_DIM;
      float s = 0.f;
#pragma unroll
      for (int ss = 0; ss < 32; ++ss) {
        const int base = ss*32 + ks8*4;
        float4 hv = *(const float4*)&h_s[b*H_DIM + base];
        float4 wv = *(const float4*)(worow + base);
        s += hv.x*wv.x + hv.y*wv.y + hv.z*wv.z + hv.w*wv.w;
      }
      s += __shfl_xor(s, 1, 64);
      s += __shfl_xor(s, 2, 64);
      s += __shfl_xor(s, 4, 64);
      if (ks8 == 0)
        out[((size_t)(b0g + b)*S_DIM + t)*OUT_DIM + oc] = s + Wob[oc];
    }
    // h_s untouched until next stage (guarded by the next barrier's __syncthreads)
  }

  // ---- h_final (from h_s, staged after last barrier)
  if (tid < BPG*JPW) {
    const int b = tid >> 5;
    const int j = tid & 31;
    out[OUT_Y_TOTAL + (size_t)(b0g + b)*H_DIM + jw0 + j] = h_s[b*H_DIM + jw0 + j];
  }
}

extern "C" void kernel_launch(void* const* d_in, const int* in_sizes, int n_in,
                              void* d_out, int out_size, void* d_ws, size_t ws_size,
                              hipStream_t stream) {
  const float* x    = (const float*)d_in[0];
  const float* h0   = (const float*)d_in[1];
  const float* ts   = (const float*)d_in[2];
  const float* tau  = (const float*)d_in[3];
  const float* Wiw  = (const float*)d_in[4];
  const float* Wib  = (const float*)d_in[5];
  const float* Wrw  = (const float*)d_in[6];
  const float* msk  = (const float*)d_in[7];
  const float* Wow  = (const float*)d_in[8];
  const float* Wob  = (const float*)d_in[9];
  const float* alp  = (const float*)d_in[10];
  const float* bet  = (const float*)d_in[11];
  const float* mu   = (const float*)d_in[12];
  const float* sg   = (const float*)d_in[13];
  float* out = (float*)d_out;

  char* ws = (char*)d_ws;
  float* hb0 = (float*)(ws);
  float* hb1 = (float*)(ws + 262144);
  float* iin = (float*)(ws + 524288);
  unsigned int* ctr = (unsigned int*)(ws + 786432);

  hipMemsetAsync(ctr, 0, 4096, stream);   // barrier counters must start at 0 every call

  hipFuncSetAttribute((const void*)ltc_kernel,
                      hipFuncAttributeMaxDynamicSharedMemorySize, LDS_BYTES);

  void* args[] = { (void*)&x, (void*)&h0, (void*)&ts, (void*)&tau,
                   (void*)&Wiw, (void*)&Wib, (void*)&Wrw, (void*)&msk,
                   (void*)&Wow, (void*)&Wob, (void*)&alp, (void*)&bet,
                   (void*)&mu, (void*)&sg, (void*)&out,
                   (void*)&hb0, (void*)&hb1, (void*)&iin, (void*)&ctr };
  hipLaunchCooperativeKernel((const void*)ltc_kernel, dim3(NWG), dim3(NTHREADS),
                             args, LDS_BYTES, stream);
}

// Round 2
// 10806.252 us; speedup vs baseline: 6.5457x; 6.5457x over previous
//
#include <hip/hip_runtime.h>

#define IN_DIM   512
#define H_DIM    1024
#define OUT_DIM  256
#define B_DIM    64
#define S_DIM    256
#define UNFOLDS  6
#define EPS_F    1e-8f

#define GB       8    // batch groups (independent sync domains)
#define GH       32   // workgroups per group
#define BPG      8    // batches per group
#define JPW      32   // h-columns owned per WG
#define NTHREADS 512
#define NWG      (GB*GH)   // 256 = one per CU

#define LDS_BYTES  ((JPW*H_DIM + BPG*H_DIM)*4)   // 128KB w + 32KB h = 160KiB

#define OUT_Y_TOTAL ((size_t)B_DIM*S_DIM*OUT_DIM)

typedef float f32x4 __attribute__((ext_vector_type(4)));

// ---- cache-bypassing (coherence-point) accesses: sc0 sc1 => miss L1+L2, serve at IF.
// These are the ONLY cross-XCD-visible ops; no cache-invalidating fences anywhere.
__device__ __forceinline__ void st_f32_cc(float* p, float v) {
  asm volatile("global_store_dword %0, %1, off sc0 sc1" :: "v"(p), "v"(v) : "memory");
}
__device__ __forceinline__ void st_u32_cc(unsigned* p, unsigned v) {
  asm volatile("global_store_dword %0, %1, off sc0 sc1" :: "v"(p), "v"(v) : "memory");
}
__device__ __forceinline__ unsigned ld_u32_cc(const unsigned* p) {
  unsigned r;
  asm volatile("global_load_dword %0, %1, off sc0 sc1\n\ts_waitcnt vmcnt(0)"
               : "=v"(r) : "v"(p) : "memory");
  return r;
}

__global__ void __launch_bounds__(NTHREADS)
ltc_kernel(const float* __restrict__ x, const float* __restrict__ h0,
           const float* __restrict__ tspan, const float* __restrict__ tau,
           const float* __restrict__ Wiw, const float* __restrict__ Wib,
           const float* __restrict__ Wrw, const float* __restrict__ wmask,
           const float* __restrict__ Wow, const float* __restrict__ Wob,
           const float* __restrict__ alpha_p, const float* __restrict__ beta_p,
           const float* __restrict__ mu_p, const float* __restrict__ sigma_p,
           float* __restrict__ out,
           float* __restrict__ hb0, float* __restrict__ hb1,
           float* __restrict__ iin_ws, unsigned* __restrict__ flags)
{
  extern __shared__ float lds[];
  float* w_s = lds;                 // [JPW][H_DIM] masked w_rec slice
  float* h_s = lds + JPW*H_DIM;     // [BPG][H_DIM] staged h for this group

  const int tid = threadIdx.x;
  const int wg  = blockIdx.x;
  const int g   = wg & 7;           // group id: blockIdx%8 -> XCD co-location heuristic
  const int w   = wg >> 3;          // 0..31 within group
  const int b0g = g * BPG;
  const int jw0 = w * JPW;
  unsigned* flag = flags + g*GH;    // this group's 32 arrival words

  // ---- init: masked w_rec slice -> LDS (plain cached loads)
  for (int idx = tid; idx < JPW*H_DIM/4; idx += NTHREADS) {
    const int j  = idx >> 8;
    const int k4 = (idx & 255) << 2;
    const size_t go = (size_t)(jw0 + j)*H_DIM + k4;
    f32x4 wv = *(const f32x4*)(Wrw + go);
    f32x4 mv = *(const f32x4*)(wmask + go);
    wv *= mv;
    *(f32x4*)&w_s[j*H_DIM + k4] = wv;
  }

  // ---- matvec thread mapping
  const int ks  = tid & 31;         // K-split lane
  const int ot  = tid >> 5;
  const int bb0 = (ot >> 3) << 2;   // 0 or 4
  const int jj0 = (ot & 7) << 2;    // 0,4,...,28
  // epilogue output owned by this lane (even ks lanes act; odd are shadows)
  const int i_ep = (ks >> 3) & 3;
  const int m_ep = (ks >> 1) & 3;
  const int b_ep = bb0 + i_ep;              // 0..7
  const int gb_ep = b0g + b_ep;
  const int jl_ep = jj0 + m_ep;             // 0..31
  const int gj_ep = jw0 + jl_ep;
  // per-output params in registers (fixed for whole kernel)
  const float mu_r  = mu_p[gj_ep];
  const float sg_r  = sigma_p[gj_ep] + EPS_F;
  const float al_r  = alpha_p[gj_ep];
  const float be_r  = beta_p[gj_ep];
  const float ta_r  = tau[gj_ep];

  // ---- W_in slice -> registers: thread (jj, kl) holds W_in[jw0+jj][kl*32 .. +32)
  const int jj = tid >> 4;          // 0..31
  const int kl = tid & 15;          // 0..15
  float win[32];
  {
    const float* src = Wiw + (size_t)(jw0 + jj)*IN_DIM + kl*32;
#pragma unroll
    for (int c = 0; c < 8; ++c) {
      f32x4 v = *(const f32x4*)(src + c*4);
      win[c*4+0] = v.x; win[c*4+1] = v.y; win[c*4+2] = v.z; win[c*4+3] = v.w;
    }
  }
  const float winb = Wib[jw0 + jj];
  const float wob_r = Wob[w*8 + ((tid>>3)&7)];   // for y epilogue

  // ---- h0 -> hb0 (coherent stores), own slice
  if (tid < BPG*JPW) {
    const int b = tid >> 5;
    const int j = tid & 31;
    st_f32_cc(hb0 + (size_t)(b0g + b)*H_DIM + jw0 + j,
              h0[(size_t)(b0g + b)*H_DIM + jw0 + j]);
  }
  asm volatile("s_waitcnt vmcnt(0)" ::: "memory");

  // ---- helpers -------------------------------------------------------------
  auto compute_iin = [&](int tt) {   // i_in(tt) -> iin_ws (plain, WG-local)
#pragma unroll 1
    for (int b = 0; b < BPG; ++b) {
      const float* xr = x + ((size_t)(b0g + b)*S_DIM + tt)*IN_DIM + kl*32;
      float s = 0.f;
#pragma unroll
      for (int c = 0; c < 8; ++c) {
        f32x4 v = *(const f32x4*)(xr + c*4);
        s += win[c*4+0]*v.x + win[c*4+1]*v.y + win[c*4+2]*v.z + win[c*4+3]*v.w;
      }
      s += __shfl_xor(s, 1, 64);
      s += __shfl_xor(s, 2, 64);
      s += __shfl_xor(s, 4, 64);
      s += __shfl_xor(s, 8, 64);
      if (kl == 0) iin_ws[((size_t)wg*BPG + b)*JPW + jj] = s + winb;
    }
  };

  auto compute_y = [&](int tt) {     // y(tt) from h_s (end-of-step-tt h)
    const int o   = tid >> 3;        // 0..63
    const int ks8 = tid & 7;
    const int b   = o >> 3;
    const int oc  = w*8 + (o & 7);
    const float* worow = Wow + (size_t)oc*H_DIM;
    float s = 0.f;
#pragma unroll
    for (int ss = 0; ss < 32; ++ss) {
      const int base = ss*32 + ks8*4;
      f32x4 hv = *(const f32x4*)&h_s[b*H_DIM + base];
      f32x4 wv = *(const f32x4*)(worow + base);
      s += hv.x*wv.x + hv.y*wv.y + hv.z*wv.z + hv.w*wv.w;
    }
    s += __shfl_xor(s, 1, 64);
    s += __shfl_xor(s, 2, 64);
    s += __shfl_xor(s, 4, 64);
    if (ks8 == 0)
      out[((size_t)(b0g + b)*S_DIM + tt)*OUT_DIM + oc] = s + wob_r;
  };

  auto barrier_wait = [&](unsigned ph) {   // wave0 polls all 32 flags coherently
    if (tid < 64) {
      const unsigned* p = flag + (tid & 31);
      while (ld_u32_cc(p) < ph) __builtin_amdgcn_s_sleep(2);
    }
    __syncthreads();
  };

  auto stage = [&](const float* hsrc) {    // group h slice -> h_s (coherent loads)
    const f32x4* src = (const f32x4*)(hsrc + (size_t)b0g*H_DIM);
    const f32x4 *p0 = src + tid, *p1 = src + tid + 512,
                *p2 = src + tid + 1024, *p3 = src + tid + 1536;
    f32x4 r0, r1, r2, r3;
    asm volatile(
      "global_load_dwordx4 %0, %4, off sc0 sc1\n\t"
      "global_load_dwordx4 %1, %5, off sc0 sc1\n\t"
      "global_load_dwordx4 %2, %6, off sc0 sc1\n\t"
      "global_load_dwordx4 %3, %7, off sc0 sc1\n\t"
      "s_waitcnt vmcnt(0)"
      : "=&v"(r0), "=&v"(r1), "=&v"(r2), "=&v"(r3)
      : "v"(p0), "v"(p1), "v"(p2), "v"(p3) : "memory");
    f32x4* hs4 = (f32x4*)h_s;
    hs4[tid] = r0; hs4[tid+512] = r1; hs4[tid+1024] = r2; hs4[tid+1536] = r3;
    __syncthreads();
  };
  // --------------------------------------------------------------------------

  __syncthreads();
  unsigned phase = 1;
  if (tid == 0) st_u32_cc(flag + w, phase);
  compute_iin(0);                    // overlap with others' arrival
  barrier_wait(phase);
  stage(hb0);

  for (int t = 0; t < S_DIM; ++t) {
#pragma unroll 1
    for (int u = 0; u < UNFOLDS; ++u) {
      float* hout = (u & 1) ? hb0 : hb1;   // step always ends in hb0

      float acc[16];
#pragma unroll
      for (int q = 0; q < 16; ++q) acc[q] = 0.f;
#pragma unroll
      for (int s8 = 0; s8 < 8; ++s8) {
        const int base = s8*128 + ks*4;    // consecutive f32x4 across lanes: conflict-free
        f32x4 hv[4], wv[4];
#pragma unroll
        for (int i = 0; i < 4; ++i) hv[i] = *(const f32x4*)&h_s[(bb0 + i)*H_DIM + base];
#pragma unroll
        for (int m = 0; m < 4; ++m) wv[m] = *(const f32x4*)&w_s[(jj0 + m)*H_DIM + base];
#pragma unroll
        for (int i = 0; i < 4; ++i)
#pragma unroll
          for (int m = 0; m < 4; ++m)
            acc[i*4+m] += hv[i].x*wv[m].x + hv[i].y*wv[m].y + hv[i].z*wv[m].z + hv[i].w*wv[m].w;
      }

      // halving-tree reduction: 16 shuffles; result r=ks>>1 lands on lane pair
#define RED_LVL(D, NH) { const bool hi = (ks & (D)) != 0;                       \
        _Pragma("unroll") for (int q = 0; q < (NH); ++q) {                      \
          float mine = hi ? acc[q+(NH)] : acc[q];                               \
          float send = hi ? acc[q]      : acc[q+(NH)];                          \
          acc[q] = mine + __shfl_xor(send, (D), 64); } }
      RED_LVL(16, 8)
      RED_LVL(8, 4)
      RED_LVL(4, 2)
      RED_LVL(2, 1)
#undef RED_LVL
      const float irec = acc[0] + __shfl_xor(acc[0], 1, 64);

      if (!(ks & 1)) {               // one output per even lane
        const float hold = h_s[b_ep*H_DIM + gj_ep];
        const float iin  = iin_ws[((size_t)wg*BPG + b_ep)*JPW + jl_ep];
        const float dsc  = tspan[(size_t)gb_ep*S_DIM + t] * (1.0f/UNFOLDS);
        const float z = (irec - mu_r) / sg_r;
        const float f = 1.0f / (1.0f + __expf(-z));
        const float dhdt = -al_r*hold + be_r*f*(iin + irec);
        st_f32_cc(hout + (size_t)gb_ep*H_DIM + gj_ep, hold + dsc*dhdt/ta_r);
      }
      asm volatile("s_waitcnt vmcnt(0)" ::: "memory");
      __syncthreads();               // all lanes' coherent h-stores are at IF

      ++phase;
      if (tid == 0) st_u32_cc(flag + w, phase);
      // overlap mandatory per-step work with other WGs' arrival skew:
      if (u == 0 && t > 0)      compute_y(t - 1);     // h_s still holds end of t-1
      if (u == 5 && t < S_DIM-1) compute_iin(t + 1);  // old iin fully consumed
      barrier_wait(phase);
      stage(hout);                   // includes trailing __syncthreads
    }
  }

  compute_y(S_DIM - 1);

  // ---- h_final (h_s holds end-of-sequence h; plain stores, flushed at kernel end)
  if (tid < BPG*JPW) {
    const int b = tid >> 5;
    const int j = tid & 31;
    out[OUT_Y_TOTAL + (size_t)(b0g + b)*H_DIM + jw0 + j] = h_s[b*H_DIM + jw0 + j];
  }
}

extern "C" void kernel_launch(void* const* d_in, const int* in_sizes, int n_in,
                              void* d_out, int out_size, void* d_ws, size_t ws_size,
                              hipStream_t stream) {
  const float* x    = (const float*)d_in[0];
  const float* h0   = (const float*)d_in[1];
  const float* ts   = (const float*)d_in[2];
  const float* tau  = (const float*)d_in[3];
  const float* Wiw  = (const float*)d_in[4];
  const float* Wib  = (const float*)d_in[5];
  const float* Wrw  = (const float*)d_in[6];
  const float* msk  = (const float*)d_in[7];
  const float* Wow  = (const float*)d_in[8];
  const float* Wob  = (const float*)d_in[9];
  const float* alp  = (const float*)d_in[10];
  const float* bet  = (const float*)d_in[11];
  const float* mu   = (const float*)d_in[12];
  const float* sg   = (const float*)d_in[13];
  float* out = (float*)d_out;

  char* ws = (char*)d_ws;
  float* hb0 = (float*)(ws);
  float* hb1 = (float*)(ws + 262144);
  float* iin = (float*)(ws + 524288);
  unsigned* flg = (unsigned*)(ws + 786432);

  hipMemsetAsync(flg, 0, 4096, stream);   // arrival flags start at 0 every call

  hipFuncSetAttribute((const void*)ltc_kernel,
                      hipFuncAttributeMaxDynamicSharedMemorySize, LDS_BYTES);

  void* args[] = { (void*)&x, (void*)&h0, (void*)&ts, (void*)&tau,
                   (void*)&Wiw, (void*)&Wib, (void*)&Wrw, (void*)&msk,
                   (void*)&Wow, (void*)&Wob, (void*)&alp, (void*)&bet,
                   (void*)&mu, (void*)&sg, (void*)&out,
                   (void*)&hb0, (void*)&hb1, (void*)&iin, (void*)&flg };
  hipLaunchCooperativeKernel((const void*)ltc_kernel, dim3(NWG), dim3(NTHREADS),
                             args, LDS_BYTES, stream);
}

// Round 3
// 9499.536 us; speedup vs baseline: 7.4461x; 1.1376x over previous
//
#include <hip/hip_runtime.h>

#define IN_DIM   512
#define H_DIM    1024
#define OUT_DIM  256
#define B_DIM    64
#define S_DIM    256
#define UNFOLDS  6
#define EPS_F    1e-8f

#define GB       8    // batch groups (independent sync domains)
#define GH       32   // workgroups per group
#define BPG      8    // batches per group
#define JPW      32   // h-columns owned per WG
#define NTHREADS 512
#define NWG      (GB*GH)   // 256 = one per CU

// LDS byte map: A-fragment-ordered h (hi/lo), reduce scratch, i_in buffer
#define A_HI_OFF 0        // [32 kt][4 kb][8 b] 16B granules = 16384
#define A_LO_OFF 16384    // 16384
#define SCR_OFF  32768    // 16 partial D-frags x 64 lanes x 16B = 16384
#define IIN_OFF  49152    // [8 b][32 j] f32 = 1024
#define LDS_BYTES 50176

#define OUT_Y_TOTAL ((size_t)B_DIM*S_DIM*OUT_DIM)

typedef float f32x4 __attribute__((ext_vector_type(4)));
typedef short s16x8 __attribute__((ext_vector_type(8)));

// ---- cache-bypassing (coherence-point) accesses: sc0 sc1 => serve at IF.
__device__ __forceinline__ void st_f32_cc(float* p, float v) {
  asm volatile("global_store_dword %0, %1, off sc0 sc1" :: "v"(p), "v"(v) : "memory");
}
__device__ __forceinline__ void st_u32_cc(unsigned* p, unsigned v) {
  asm volatile("global_store_dword %0, %1, off sc0 sc1" :: "v"(p), "v"(v) : "memory");
}
__device__ __forceinline__ unsigned ld_u32_cc(const unsigned* p) {
  unsigned r;
  asm volatile("global_load_dword %0, %1, off sc0 sc1\n\ts_waitcnt vmcnt(0)"
               : "=v"(r) : "v"(p) : "memory");
  return r;
}

// split f32 -> (bf16 hi, bf16 lo) by truncation; hi+lo reconstructs to ~2^-16 rel.
__device__ __forceinline__ void split_bf16(f32x4 f0, f32x4 f1, s16x8* hi, s16x8* lo) {
  union { unsigned u[4]; s16x8 s; } H, L;
  float fv[8];
#pragma unroll
  for (int e = 0; e < 4; ++e) { fv[e] = f0[e]; fv[e+4] = f1[e]; }
#pragma unroll
  for (int d = 0; d < 4; ++d) {
    unsigned u0 = __float_as_uint(fv[2*d]);
    unsigned u1 = __float_as_uint(fv[2*d+1]);
    unsigned t0 = u0 & 0xffff0000u, t1 = u1 & 0xffff0000u;
    H.u[d] = (u0 >> 16) | t1;
    L.u[d] = ((__float_as_uint(fv[2*d]   - __uint_as_float(t0))) >> 16)
           | ((__float_as_uint(fv[2*d+1] - __uint_as_float(t1))) & 0xffff0000u);
  }
  *hi = H.s; *lo = L.s;
}

__global__ void __launch_bounds__(NTHREADS)
ltc_kernel(const float* __restrict__ x, const float* __restrict__ h0,
           const float* __restrict__ tspan, const float* __restrict__ tau,
           const float* __restrict__ Wiw, const float* __restrict__ Wib,
           const float* __restrict__ Wrw, const float* __restrict__ wmask,
           const float* __restrict__ Wow, const float* __restrict__ Wob,
           const float* __restrict__ alpha_p, const float* __restrict__ beta_p,
           const float* __restrict__ mu_p, const float* __restrict__ sigma_p,
           float* __restrict__ out,
           float* __restrict__ hb0, float* __restrict__ hb1,
           float* __restrict__ iin_unused, unsigned* __restrict__ flags)
{
  extern __shared__ char ldsc[];

  const int tid = threadIdx.x;
  const int wg  = blockIdx.x;
  const int g   = wg & 7;           // group id (XCD co-location heuristic)
  const int w   = wg >> 3;          // 0..31 within group
  const int b0g = g * BPG;
  const int jw0 = w * JPW;
  unsigned* flag = flags + g*GH;

  const int lane = tid & 63;
  const int kp   = tid >> 6;        // wave id = K-part (8-way K split)

  // ---- B-fragments (masked w_rec, split bf16) -> REGISTERS, permanent.
  // wave kp owns kt = kp*4+i (i<4); per kt both n-tiles (j 0..15, 16..31).
  // B[k][n]: lane holds w[jw0+nt*16+(lane&15)][kt*32+(lane>>4)*8 ..+8]
  s16x8 bh[4][2], bl[4][2];
#pragma unroll
  for (int i = 0; i < 4; ++i) {
    const int k0 = (kp*4 + i)*32 + (lane >> 4)*8;
#pragma unroll
    for (int nt = 0; nt < 2; ++nt) {
      const int j = jw0 + nt*16 + (lane & 15);
      const size_t go = (size_t)j*H_DIM + k0;
      f32x4 w0 = *(const f32x4*)(Wrw + go);
      f32x4 w1 = *(const f32x4*)(Wrw + go + 4);
      f32x4 m0 = *(const f32x4*)(wmask + go);
      f32x4 m1 = *(const f32x4*)(wmask + go + 4);
      w0 *= m0; w1 *= m1;
      split_bf16(w0, w1, &bh[i][nt], &bl[i][nt]);
    }
  }

  // ---- W_in slice -> registers: thread (jj, kl) holds W_in[jw0+jj][kl*32 ..+32)
  const int jj = tid >> 4;          // 0..31
  const int kl = tid & 15;          // 0..15
  float win[32];
  {
    const float* src = Wiw + (size_t)(jw0 + jj)*IN_DIM + kl*32;
#pragma unroll
    for (int c = 0; c < 8; ++c) {
      f32x4 v = *(const f32x4*)(src + c*4);
      win[c*4+0] = v.x; win[c*4+1] = v.y; win[c*4+2] = v.z; win[c*4+3] = v.w;
    }
  }
  const float winb  = Wib[jw0 + jj];
  const float wob_r = Wob[w*8 + ((tid>>3)&7)];

  // ---- epilogue thread mapping: t <-> (b, j, hi-shadow); 256 real outputs
  const int b_e    = tid >> 6;             // 0..7
  const int jf     = (tid & 63) >> 1;      // 0..31  (= local j)
  const int hi_e   = tid & 1;              // shadow thread (garbage D rows)
  const int nt_e   = jf >> 4;
  const int lane_e = ((b_e >> 2) << 4) + (jf & 15) + (hi_e << 5);
  const int r_e    = b_e & 3;              // D reg index (wave-uniform)
  const int gj_e   = jw0 + jf;
  const int gb_e   = b0g + b_e;
  const float mu_r  = mu_p[gj_e];
  const float sgi_r = 1.0f / (sigma_p[gj_e] + EPS_F);
  const float al_r  = alpha_p[gj_e];
  const float be_r  = beta_p[gj_e];
  const float ti_r  = 1.0f / tau[gj_e];

  // ---- h0 -> hb0 (coherent), own slice
  if (tid < BPG*JPW) {
    const int b = tid >> 5;
    const int j = tid & 31;
    st_f32_cc(hb0 + (size_t)(b0g + b)*H_DIM + jw0 + j,
              h0[(size_t)(b0g + b)*H_DIM + jw0 + j]);
  }
  asm volatile("s_waitcnt vmcnt(0)" ::: "memory");

  // ---- helpers -------------------------------------------------------------
  auto compute_iin = [&](int tt) {   // i_in(tt) -> LDS iin buffer
#pragma unroll 1
    for (int b = 0; b < BPG; ++b) {
      const float* xr = x + ((size_t)(b0g + b)*S_DIM + tt)*IN_DIM + kl*32;
      float s = 0.f;
#pragma unroll
      for (int c = 0; c < 8; ++c) {
        f32x4 v = *(const f32x4*)(xr + c*4);
        s += win[c*4+0]*v.x + win[c*4+1]*v.y + win[c*4+2]*v.z + win[c*4+3]*v.w;
      }
      s += __shfl_xor(s, 1, 64);
      s += __shfl_xor(s, 2, 64);
      s += __shfl_xor(s, 4, 64);
      s += __shfl_xor(s, 8, 64);
      if (kl == 0) *(float*)(ldsc + IIN_OFF + (b*JPW + jj)*4) = s + winb;
    }
  };

  auto compute_y = [&](int tt) {     // y(tt) from staged h fragments (hi+lo)
    const int o = tid >> 3, ks8 = tid & 7;
    const int bb = o >> 3, oc = w*8 + (o & 7);
    const float* worow = Wow + (size_t)oc*H_DIM;
    float s = 0.f;
#pragma unroll
    for (int ss = 0; ss < 16; ++ss) {
      const int kidx = ss*8 + ks8;   // 8-float chunk index (0..127)
      const int gbo = (kidx >> 2)*512 + (kidx & 3)*128 + bb*16;
      s16x8 hh = *(const s16x8*)(ldsc + A_HI_OFF + gbo);
      s16x8 ll = *(const s16x8*)(ldsc + A_LO_OFF + gbo);
      f32x4 w0 = *(const f32x4*)(worow + kidx*8);
      f32x4 w1 = *(const f32x4*)(worow + kidx*8 + 4);
#pragma unroll
      for (int e = 0; e < 4; ++e) {
        float hf0 = __uint_as_float(((unsigned)(unsigned short)hh[e]) << 16)
                  + __uint_as_float(((unsigned)(unsigned short)ll[e]) << 16);
        float hf1 = __uint_as_float(((unsigned)(unsigned short)hh[e+4]) << 16)
                  + __uint_as_float(((unsigned)(unsigned short)ll[e+4]) << 16);
        s += hf0 * w0[e] + hf1 * w1[e];
      }
    }
    s += __shfl_xor(s, 1, 64);
    s += __shfl_xor(s, 2, 64);
    s += __shfl_xor(s, 4, 64);
    if (ks8 == 0)
      out[((size_t)(b0g + bb)*S_DIM + tt)*OUT_DIM + oc] = s + wob_r;
  };

  auto barrier_wait = [&](unsigned ph) {   // wave0 polls all 32 flags coherently
    if (tid < 64) {
      const unsigned* p = flag + (tid & 31);
      while (ld_u32_cc(p) < ph) __builtin_amdgcn_s_sleep(2);
    }
    __syncthreads();
  };

  // stage: group h slice (coherent) -> A-fragment-ordered LDS, split bf16.
  // thread t -> subblocks s=t and s=t+512; s: b=s&7, kb=(s>>3)&3, kt=s>>5.
  auto stage = [&](const float* hsrc) {
    const int b   = tid & 7;
    const int kb  = (tid >> 3) & 3;
    const int kt1 = tid >> 5;                 // 0..15 (second: +16)
    const float* p0 = hsrc + (size_t)(b0g + b)*H_DIM + kt1*32 + kb*8;
    const float* p1 = p0 + 512;               // kt1+16
    f32x4 r0, r1, r2, r3;
    asm volatile(
      "global_load_dwordx4 %0, %4, off sc0 sc1\n\t"
      "global_load_dwordx4 %1, %5, off sc0 sc1\n\t"
      "global_load_dwordx4 %2, %6, off sc0 sc1\n\t"
      "global_load_dwordx4 %3, %7, off sc0 sc1\n\t"
      "s_waitcnt vmcnt(0)"
      : "=&v"(r0), "=&v"(r1), "=&v"(r2), "=&v"(r3)
      : "v"(p0), "v"(p0+4), "v"(p1), "v"(p1+4) : "memory");
    const int d1 = kt1*512 + kb*128 + b*16;
    const int d2 = d1 + 16*512;
    s16x8 h1, l1, h2, l2;
    split_bf16(r0, r1, &h1, &l1);
    split_bf16(r2, r3, &h2, &l2);
    *(s16x8*)(ldsc + A_HI_OFF + d1) = h1;
    *(s16x8*)(ldsc + A_LO_OFF + d1) = l1;
    *(s16x8*)(ldsc + A_HI_OFF + d2) = h2;
    *(s16x8*)(ldsc + A_LO_OFF + d2) = l2;
    __syncthreads();
  };
  // --------------------------------------------------------------------------

  __syncthreads();
  unsigned phase = 1;
  if (tid == 0) st_u32_cc(flag + w, phase);
  compute_iin(0);                    // overlap with others' arrival
  barrier_wait(phase);
  stage(hb0);

  for (int t = 0; t < S_DIM; ++t) {
#pragma unroll 1
    for (int u = 0; u < UNFOLDS; ++u) {
      float* hout = (u & 1) ? hb0 : hb1;   // step always ends in hb0

      // ---- MFMA phase: 3-split bf16, A from LDS frags, B from registers
      f32x4 acc0 = {0.f,0.f,0.f,0.f}, acc1 = {0.f,0.f,0.f,0.f};
      const char* Ab = ldsc + (lane >> 4)*128 + (lane & 7)*16;
#pragma unroll
      for (int i = 0; i < 4; ++i) {
        const int off = (kp*4 + i)*512;
        s16x8 ah = *(const s16x8*)(Ab + A_HI_OFF + off);
        s16x8 al = *(const s16x8*)(Ab + A_LO_OFF + off);
        acc0 = __builtin_amdgcn_mfma_f32_16x16x32_bf16(ah, bh[i][0], acc0, 0,0,0);
        acc1 = __builtin_amdgcn_mfma_f32_16x16x32_bf16(ah, bh[i][1], acc1, 0,0,0);
        acc0 = __builtin_amdgcn_mfma_f32_16x16x32_bf16(al, bh[i][0], acc0, 0,0,0);
        acc1 = __builtin_amdgcn_mfma_f32_16x16x32_bf16(al, bh[i][1], acc1, 0,0,0);
        acc0 = __builtin_amdgcn_mfma_f32_16x16x32_bf16(ah, bl[i][0], acc0, 0,0,0);
        acc1 = __builtin_amdgcn_mfma_f32_16x16x32_bf16(ah, bl[i][1], acc1, 0,0,0);
      }
      *(f32x4*)(ldsc + SCR_OFF + ((kp*2+0)*64 + lane)*16) = acc0;
      *(f32x4*)(ldsc + SCR_OFF + ((kp*2+1)*64 + lane)*16) = acc1;
      __syncthreads();

      // ---- K-part reduce (all 512 threads) + epilogue (1 output each)
      float irec = 0.f;
#pragma unroll
      for (int p = 0; p < 8; ++p) {
        f32x4 v = *(const f32x4*)(ldsc + SCR_OFF + ((p*2 + nt_e)*64 + lane_e)*16);
        irec += (r_e == 0) ? v[0] : (r_e == 1) ? v[1] : (r_e == 2) ? v[2] : v[3];
      }
      {
        const int ho  = (gj_e >> 5)*512 + ((gj_e >> 3) & 3)*128 + b_e*16 + (gj_e & 7)*2;
        const unsigned hh = *(const unsigned short*)(ldsc + A_HI_OFF + ho);
        const unsigned hl = *(const unsigned short*)(ldsc + A_LO_OFF + ho);
        const float hold = __uint_as_float(hh << 16) + __uint_as_float(hl << 16);
        const float iin  = *(const float*)(ldsc + IIN_OFF + (b_e*JPW + jf)*4);
        const float dsc  = tspan[(size_t)gb_e*S_DIM + t] * (1.0f/UNFOLDS);
        const float zz   = (irec - mu_r) * sgi_r;
        const float ff   = 1.0f / (1.0f + __expf(-zz));
        const float dhdt = -al_r*hold + be_r*ff*(iin + irec);
        const float hnew = hold + dsc*dhdt*ti_r;
        if (!hi_e) {
          st_f32_cc(hout + (size_t)gb_e*H_DIM + gj_e, hnew);
          if (t == S_DIM-1 && u == UNFOLDS-1)
            out[OUT_Y_TOTAL + (size_t)gb_e*H_DIM + gj_e] = hnew;
        }
      }
      asm volatile("s_waitcnt vmcnt(0)" ::: "memory");
      __syncthreads();               // all coherent h-stores at IF

      ++phase;
      if (tid == 0) st_u32_cc(flag + w, phase);
      // overlap mandatory per-step work with other WGs' arrival skew:
      if (u == 0 && t > 0)           compute_y(t - 1);   // frags still hold h_end(t-1)
      if (u == UNFOLDS-1 && t < S_DIM-1) compute_iin(t + 1);
      barrier_wait(phase);
      stage(hout);                   // includes trailing __syncthreads
    }
  }

  compute_y(S_DIM - 1);
}

extern "C" void kernel_launch(void* const* d_in, const int* in_sizes, int n_in,
                              void* d_out, int out_size, void* d_ws, size_t ws_size,
                              hipStream_t stream) {
  const float* x    = (const float*)d_in[0];
  const float* h0   = (const float*)d_in[1];
  const float* ts   = (const float*)d_in[2];
  const float* tau  = (const float*)d_in[3];
  const float* Wiw  = (const float*)d_in[4];
  const float* Wib  = (const float*)d_in[5];
  const float* Wrw  = (const float*)d_in[6];
  const float* msk  = (const float*)d_in[7];
  const float* Wow  = (const float*)d_in[8];
  const float* Wob  = (const float*)d_in[9];
  const float* alp  = (const float*)d_in[10];
  const float* bet  = (const float*)d_in[11];
  const float* mu   = (const float*)d_in[12];
  const float* sg   = (const float*)d_in[13];
  float* out = (float*)d_out;

  char* ws = (char*)d_ws;
  float* hb0 = (float*)(ws);
  float* hb1 = (float*)(ws + 262144);
  float* iin = (float*)(ws + 524288);   // unused (kept for arg shape)
  unsigned* flg = (unsigned*)(ws + 786432);

  hipMemsetAsync(flg, 0, 4096, stream);   // arrival flags start at 0 every call

  hipFuncSetAttribute((const void*)ltc_kernel,
                      hipFuncAttributeMaxDynamicSharedMemorySize, LDS_BYTES);

  void* args[] = { (void*)&x, (void*)&h0, (void*)&ts, (void*)&tau,
                   (void*)&Wiw, (void*)&Wib, (void*)&Wrw, (void*)&msk,
                   (void*)&Wow, (void*)&Wob, (void*)&alp, (void*)&bet,
                   (void*)&mu, (void*)&sg, (void*)&out,
                   (void*)&hb0, (void*)&hb1, (void*)&iin, (void*)&flg };
  hipLaunchCooperativeKernel((const void*)ltc_kernel, dim3(NWG), dim3(NTHREADS),
                             args, LDS_BYTES, stream);
}